// Round 2
// baseline (362.413 us; speedup 1.0000x reference)
//
#include <hip/hip_runtime.h>
#include <hip/hip_bf16.h>
#include <math.h>

// Shapes fixed by the reference setup.
#define BB 256
#define NN 4096
#define DD 64
#define TPB 256
#define CHUNK (NN / TPB)   // 16 elements per thread in the scan kernel

// ---------------- Kernel 1: scores[b,n] = dot(X[b,n,:], W) + b0 ----------------
// 16 lanes cooperate on one row: lane d4 handles dims [4*d4, 4*d4+4) via float4.
// Wave (64 lanes) covers 4 rows -> fully coalesced 1KiB global reads per instr.
__global__ __launch_bounds__(256) void scores_kernel(
    const float* __restrict__ X, const float* __restrict__ W,
    const float* __restrict__ bptr, float* __restrict__ scores, int total_rows) {
  __shared__ float4 Wl[16];
  if (threadIdx.x < 16) Wl[threadIdx.x] = ((const float4*)W)[threadIdx.x];
  __syncthreads();
  const float b0 = bptr[0];
  const int lane16 = threadIdx.x & 15;
  const int rowInBlk = threadIdx.x >> 4;            // 0..15
  const float4 w = Wl[lane16];
  const long long stride = (long long)gridDim.x * 16;
  for (long long row = (long long)blockIdx.x * 16 + rowInBlk; row < total_rows; row += stride) {
    const float4* xp = (const float4*)(X + row * DD);
    float4 x = xp[lane16];
    float v = x.x * w.x + x.y * w.y + x.z * w.z + x.w * w.w;
    v += __shfl_xor(v, 1);
    v += __shfl_xor(v, 2);
    v += __shfl_xor(v, 4);
    v += __shfl_xor(v, 8);
    if (lane16 == 0) scores[row] = v + b0;
  }
}

// ---------------- Kernel 2: per-row gather + reverse cumulative LSE ----------------
// One block per row b. Thread t owns contiguous elements [t*16, t*16+16).
// Partial LSE represented as (m, s): value = m + log(s).
__global__ __launch_bounds__(256) void pl_row_kernel(
    const float* __restrict__ scores, const int* __restrict__ rankings,
    float* __restrict__ rowsum) {
  const int b = blockIdx.x;
  const int t = threadIdx.x;
  const float* srow = scores + (size_t)b * NN;
  const int*   rrow = rankings + (size_t)b * NN;
  const int base = t * CHUNK;

  // Gather this thread's 16 ranked scores (ranking loads are 64B/thread, coalesced).
  float xv[CHUNK];
  const int4* rr = (const int4*)(rrow + base);
  #pragma unroll
  for (int q = 0; q < CHUNK / 4; ++q) {
    int4 r4 = rr[q];
    xv[q * 4 + 0] = srow[r4.x];
    xv[q * 4 + 1] = srow[r4.y];
    xv[q * 4 + 2] = srow[r4.z];
    xv[q * 4 + 3] = srow[r4.w];
  }

  // Chunk-total LSE (reverse order, though order doesn't matter for the total).
  float m = -INFINITY, s = 0.f;
  #pragma unroll
  for (int j = CHUNK - 1; j >= 0; --j) {
    float x = xv[j];
    float mn = fmaxf(m, x);
    s = s * __expf(m - mn) + __expf(x - mn);
    m = mn;
  }

  // Hillis-Steele reverse inclusive scan of (m,s) across the 256 threads.
  __shared__ float sm[2][TPB], ss[2][TPB];
  sm[0][t] = m; ss[0][t] = s;
  __syncthreads();
  int src = 0;
  for (int off = 1; off < TPB; off <<= 1) {
    float mc = sm[src][t], sc = ss[src][t];
    if (t + off < TPB) {
      float mo = sm[src][t + off], so = ss[src][t + off];
      float mn = fmaxf(mc, mo);
      sc = sc * __expf(mc - mn) + so * __expf(mo - mn);
      mc = mn;
    }
    sm[src ^ 1][t] = mc; ss[src ^ 1][t] = sc;
    __syncthreads();
    src ^= 1;
  }
  // Exclusive reverse suffix for this thread = inclusive suffix of thread t+1.
  float rm, rs;
  if (t == TPB - 1) { rm = -INFINITY; rs = 0.f; }
  else             { rm = sm[src][t + 1]; rs = ss[src][t + 1]; }

  // Second pass: per-element suffix LSE and accumulate (x_i - denom_i).
  float acc = 0.f;
  #pragma unroll
  for (int j = CHUNK - 1; j >= 0; --j) {
    float x = xv[j];
    float mn = fmaxf(rm, x);
    rs = rs * __expf(rm - mn) + __expf(x - mn);
    rm = mn;
    float denom = rm + __logf(rs);
    acc += x - denom;
  }

  // Block reduction of acc.
  __shared__ float red[TPB];
  red[t] = acc;
  __syncthreads();
  for (int off = TPB / 2; off > 0; off >>= 1) {
    if (t < off) red[t] += red[t + off];
    __syncthreads();
  }
  if (t == 0) rowsum[b] = red[0];
}

// ---------------- Kernel 3: out = -sum(rowsum) / B ----------------
__global__ __launch_bounds__(256) void final_kernel(
    const float* __restrict__ rowsum, float* __restrict__ out) {
  const int t = threadIdx.x;
  __shared__ float red[TPB];
  red[t] = (t < BB) ? rowsum[t] : 0.f;
  __syncthreads();
  for (int off = TPB / 2; off > 0; off >>= 1) {
    if (t < off) red[t] += red[t + off];
    __syncthreads();
  }
  if (t == 0) out[0] = -red[0] / (float)BB;
}

extern "C" void kernel_launch(void* const* d_in, const int* in_sizes, int n_in,
                              void* d_out, int out_size, void* d_ws, size_t ws_size,
                              hipStream_t stream) {
  const float* X  = (const float*)d_in[0];
  const float* W  = (const float*)d_in[1];
  const float* bp = (const float*)d_in[2];
  const int*   rk = (const int*)d_in[3];
  float* out = (float*)d_out;

  float* scores = (float*)d_ws;                       // B*N floats = 4 MiB
  float* rowsum = scores + (size_t)BB * NN;           // B floats

  const int total_rows = BB * NN;                     // 1,048,576
  scores_kernel<<<2048, TPB, 0, stream>>>(X, W, bp, scores, total_rows);
  pl_row_kernel<<<BB, TPB, 0, stream>>>(scores, rk, rowsum);
  final_kernel<<<1, TPB, 0, stream>>>(rowsum, out);
}

// Round 3
// 361.759 us; speedup vs baseline: 1.0018x; 1.0018x over previous
//
#include <hip/hip_runtime.h>
#include <math.h>

// Shapes fixed by the reference setup.
#define BB 256
#define NN 4096
#define DD 64
#define TPB 1024
#define CH (NN / TPB)   // 4 ranked elements per thread

// One block per batch row b:
//   phase 1: scores[n] = dot(X[b,n,:], W) + b0 into LDS (16 lanes/row, coalesced float4)
//   phase 2: gather by rankings from LDS, reverse cumulative logsumexp via
//            (m,s) pairs: intra-wave shfl_down scan -> 16 wave totals -> combine
//   phase 3: block partial of sum(x_i - suffix_lse_i), atomicAdd into out.
__global__ __launch_bounds__(TPB) void pl_fused_kernel(
    const float* __restrict__ X, const float* __restrict__ W,
    const float* __restrict__ bptr, const int* __restrict__ rankings,
    float* __restrict__ out) {
  __shared__ float srow[NN];                 // 16 KB score row
  __shared__ float wm_s[16], ws_s[16];       // per-wave inclusive totals
  __shared__ float em_s[16], es_s[16];       // per-wave exclusive suffix (higher waves)
  __shared__ float red_s[16];

  const int b = blockIdx.x;
  const int t = threadIdx.x;
  const int lane16 = t & 15;
  const int g = t >> 4;                      // 0..63: row-in-iteration
  const int l = t & 63;                      // lane in wave
  const int wv = t >> 6;                     // wave id 0..15

  const float4 w4 = ((const float4*)W)[lane16];
  const float b0 = bptr[0];
  const float* Xb = X + (size_t)b * (NN * DD);

  // ---- phase 1: scores into LDS (block reads contiguous 16KB per iteration) ----
  #pragma unroll 4
  for (int it = 0; it < NN / 64; ++it) {
    const int n = it * 64 + g;
    const float4 x = ((const float4*)(Xb + (size_t)n * DD))[lane16];
    float v = x.x * w4.x + x.y * w4.y + x.z * w4.z + x.w * w4.w;
    v += __shfl_xor(v, 1);
    v += __shfl_xor(v, 2);
    v += __shfl_xor(v, 4);
    v += __shfl_xor(v, 8);
    if (lane16 == 0) srow[n] = v + b0;
  }
  __syncthreads();

  // ---- phase 2: gather this thread's CH ranked scores ----
  const int4 r4 = *(const int4*)(rankings + (size_t)b * NN + t * CH);
  float xv[CH];
  xv[0] = srow[r4.x]; xv[1] = srow[r4.y]; xv[2] = srow[r4.z]; xv[3] = srow[r4.w];

  // chunk-total LSE in (m,s) form, reverse order; seeded finite (no -inf here)
  float m = xv[CH - 1], s = 1.f;
  #pragma unroll
  for (int j = CH - 2; j >= 0; --j) {
    const float mn = fmaxf(m, xv[j]);
    s = s * __expf(m - mn) + __expf(xv[j] - mn);
    m = mn;
  }

  // intra-wave reverse inclusive scan (higher lane = later element)
  float im = m, is = s;
  #pragma unroll
  for (int off = 1; off < 64; off <<= 1) {
    const float om = __shfl_down(im, off);
    const float os = __shfl_down(is, off);
    if (l + off < 64) {
      const float mn = fmaxf(im, om);
      is = is * __expf(im - mn) + os * __expf(om - mn);
      im = mn;
    }
  }
  if (l == 0) { wm_s[wv] = im; ws_s[wv] = is; }   // wave-total LSE
  __syncthreads();

  // wave 0 scans the 16 wave totals (reverse), producing exclusive suffixes
  if (wv == 0) {
    float am = (l < 16) ? wm_s[l] : -INFINITY;
    float as = (l < 16) ? ws_s[l] : 0.f;
    #pragma unroll
    for (int off = 1; off < 16; off <<= 1) {
      const float om = __shfl_down(am, off);
      const float os = __shfl_down(as, off);
      if (l + off < 16) {
        const float mn = fmaxf(am, om);
        as = as * __expf(am - mn) + os * __expf(om - mn);
        am = mn;
      }
    }
    float em2 = __shfl_down(am, 1);   // exclusive = inclusive of wave l+1
    float es2 = __shfl_down(as, 1);
    if (l == 15) { em2 = -INFINITY; es2 = 0.f; }
    if (l < 16) { em_s[l] = em2; es_s[l] = es2; }
  }
  __syncthreads();

  // per-thread exclusive suffix = (within-wave lanes l+1..63) ⊕ (waves wv+1..15)
  float xm = __shfl_down(im, 1);
  float xs = __shfl_down(is, 1);
  if (l == 63) { xm = -INFINITY; xs = 0.f; }
  const float hm = em_s[wv], hs = es_s[wv];
  float rm, rs;
  if (xm == -INFINITY)      { rm = hm; rs = hs; }
  else if (hm == -INFINITY) { rm = xm; rs = xs; }
  else {
    const float mn = fmaxf(xm, hm);
    rs = xs * __expf(xm - mn) + hs * __expf(hm - mn);
    rm = mn;
  }

  // ---- phase 3: per-element suffix LSE + accumulate (x_i - denom_i) ----
  float acc = 0.f;
  #pragma unroll
  for (int j = CH - 1; j >= 0; --j) {
    const float x = xv[j];
    const float mn = fmaxf(rm, x);
    rs = rs * __expf(rm - mn) + __expf(x - mn);   // expf(-inf)=0 handles seed
    rm = mn;
    acc += x - (rm + __logf(rs));
  }

  // block reduction and atomic accumulate of -acc/B
  #pragma unroll
  for (int off = 32; off > 0; off >>= 1) acc += __shfl_xor(acc, off);
  if (l == 0) red_s[wv] = acc;
  __syncthreads();
  if (t == 0) {
    float tot = 0.f;
    #pragma unroll
    for (int i = 0; i < 16; ++i) tot += red_s[i];
    atomicAdd(out, -tot * (1.f / (float)BB));
  }
}

extern "C" void kernel_launch(void* const* d_in, const int* in_sizes, int n_in,
                              void* d_out, int out_size, void* d_ws, size_t ws_size,
                              hipStream_t stream) {
  const float* X  = (const float*)d_in[0];
  const float* W  = (const float*)d_in[1];
  const float* bp = (const float*)d_in[2];
  const int*   rk = (const int*)d_in[3];
  float* out = (float*)d_out;

  // out is poisoned 0xAA before every launch; zero it (graph-capturable memset).
  hipMemsetAsync(out, 0, sizeof(float) * (size_t)out_size, stream);
  pl_fused_kernel<<<BB, TPB, 0, stream>>>(X, W, bp, rk, out);
}